// Round 3
// baseline (368.810 us; speedup 1.0000x reference)
//
#include <hip/hip_runtime.h>
#include <stdint.h>

#define M_DIM 4096
#define T_DIM 2048
#define N_OUT 2024
#define N_PAD 2048
#define WIN   25
#define K_DIM 4096
#define K_HALF 2048

typedef float f32x4 __attribute__((ext_vector_type(4)));

__device__ __forceinline__ unsigned short f2bf(float x) {
  unsigned u = __float_as_uint(x);
  u += 0x7FFF + ((u >> 16) & 1);           // round-to-nearest-even
  return (unsigned short)(u >> 16);
}
__device__ __forceinline__ float bf2f(unsigned short h) {
  return __uint_as_float(((unsigned)h) << 16);
}

__device__ __forceinline__ void gl2lds16(const void* g, void* l) {
  // 16B-wide async global->LDS; HW dest = wave-uniform base + lane*16
  __builtin_amdgcn_global_load_lds(
      (const __attribute__((address_space(1))) unsigned int*)g,
      (__attribute__((address_space(3))) unsigned int*)l, 16, 0, 0);
}

// pack 4 floats -> 4 e4m3 bytes (one dword)
__device__ __forceinline__ int pk_fp8x4(float a, float b, float c, float d) {
  int w = __builtin_amdgcn_cvt_pk_fp8_f32(a, b, 0, false);
  w = __builtin_amdgcn_cvt_pk_fp8_f32(c, d, w, true);
  return w;
}

// ---------- Fused prep: wcast | conv | transpose | out-zero ----------
// R10: one launch instead of three + zero-fill. Block ranges:
//   [0, 8192)          : W8 = e4m3(sigmoid(alphas)), diag -> 0
//   [8192, 40960)      : Sbf = bf16(softplus(depthwise_conv(ys, repro)))
//   [40960, 43008)     : BT8[n][k] = e4m3(ys[k][n+24]), zero-pad n>=2024
//   [43008, 51104)     : out = 0  (required: k_gemm halves atomicAdd into it)
#define NB_WCAST 8192
#define NB_CONV  32768
#define NB_TRANS 2048
#define NB_ZERO  8096
#define B_CONV   NB_WCAST
#define B_TRANS  (B_CONV + NB_CONV)
#define B_ZERO   (B_TRANS + NB_TRANS)
#define NB_PREP  (B_ZERO + NB_ZERO)

__global__ __launch_bounds__(256) void k_prep(const float* __restrict__ alphas,
                                              const float* __restrict__ ys,
                                              const float* __restrict__ repro,
                                              unsigned char* __restrict__ W8,
                                              unsigned char* __restrict__ BT8,
                                              unsigned short* __restrict__ Sbf,
                                              float* __restrict__ out) {
  __shared__ __align__(16) char smem[64 * 65 * 4];   // max of branch needs (16.6 KB)
  const int bid = blockIdx.x;
  const int tid = threadIdx.x;

  if (bid < B_CONV) {
    // ---- wcast ----
    size_t i8 = ((size_t)bid * 256 + tid) * 8;
    const float4 v0 = *(const float4*)(alphas + i8);
    const float4 v1 = *(const float4*)(alphas + i8 + 4);
    int row = (int)(i8 >> 12);
    int col = (int)(i8 & 4095);
    float a[8] = {v0.x, v0.y, v0.z, v0.w, v1.x, v1.y, v1.z, v1.w};
    float w[8];
#pragma unroll
    for (int j = 0; j < 8; ++j)
      w[j] = (row == col + j) ? 0.f : 1.f / (1.f + __expf(-a[j]));
    int p0 = pk_fp8x4(w[0], w[1], w[2], w[3]);
    int p1 = pk_fp8x4(w[4], w[5], w[6], w[7]);
    *(uint2*)(W8 + i8) = uint2{(unsigned)p0, (unsigned)p1};
  } else if (bid < B_TRANS) {
    // ---- conv ----
    float* sy = (float*)smem;          // 280 floats
    float* sr = sy + 280;              // 25 floats
    int b  = bid - B_CONV;
    int m  = b >> 3;
    int j0 = (b & 7) * 256;
    sy[tid] = ys[(size_t)m * T_DIM + j0 + tid];
    if (tid < WIN - 1) {
      int jj = j0 + 256 + tid;
      sy[256 + tid] = (jj < T_DIM) ? ys[(size_t)m * T_DIM + jj] : 0.f;
    }
    if (tid < WIN) sr[tid] = repro[m * WIN + tid];
    __syncthreads();
    int j = j0 + tid;
    float z = 0.f;
#pragma unroll
    for (int k = 0; k < WIN; ++k) z += sy[tid + k] * sr[k];
    float sp = fmaxf(z, 0.f) + log1pf(__expf(-fabsf(z)));
    Sbf[(size_t)m * N_PAD + j] = (j < N_OUT) ? f2bf(sp) : (unsigned short)0;
  } else if (bid < B_ZERO) {
    // ---- transpose ----
    float (*t)[65] = (float (*)[65])smem;
    int b  = bid - B_TRANS;
    int n0 = (b & 31) * 64;
    int k0 = (b >> 5) * 64;
    int tx = tid & 63;
    int ty = tid >> 6;
#pragma unroll
    for (int r = 0; r < 16; ++r) {
      int kk = k0 + ty + r * 4;
      int n = n0 + tx;
      t[ty + r * 4][tx] = (n < N_OUT) ? ys[(size_t)kk * T_DIM + n + (WIN - 1)] : 0.f;
    }
    __syncthreads();
    int nl = tid >> 2;
    int kc = (tid & 3) * 16;
    unsigned wds[4];
#pragma unroll
    for (int w = 0; w < 4; ++w)
      wds[w] = (unsigned)pk_fp8x4(t[kc + 4 * w][nl], t[kc + 4 * w + 1][nl],
                                  t[kc + 4 * w + 2][nl], t[kc + 4 * w + 3][nl]);
    *(uint4*)(BT8 + (size_t)(n0 + nl) * K_DIM + k0 + kc) =
        uint4{wds[0], wds[1], wds[2], wds[3]};
  } else {
    // ---- zero out ----
    size_t idx = ((size_t)(bid - B_ZERO) * 256 + tid);
    ((float4*)out)[idx] = float4{0.f, 0.f, 0.f, 0.f};
  }
}

// ---------- GEMM: C = W8 @ BT8^T (fp8 MFMA), out += beta * (S + C_half) ----------
// R10: split-K=2 -> 1024 blocks = 4 blocks/CU; LDS cut to 2 buffers (32 KB)
// so 4 fit; launch_bounds(512,8) -> 32 waves/CU (the cap; R9 proved
// throughput = resident waves / kstep latency, and 16 waves left half the
// cap idle). Staging traffic unchanged at 512 MB (each block stages only
// its K-half). Halves combine via unsafeAtomicAdd into pre-zeroed out:
// exactly 2 commutative f32 adds per element -> deterministic.
// Ping-pong counted vmcnt(2), raw s_barrier, XOR chunk swizzle unchanged.
__global__ __launch_bounds__(512, 8) void k_gemm(const unsigned char* __restrict__ W8,
                                                 const unsigned char* __restrict__ BT8,
                                                 const unsigned short* __restrict__ Sbf,
                                                 const float* __restrict__ b0,
                                                 const float* __restrict__ b1,
                                                 float* __restrict__ out) {
  __shared__ __align__(64) unsigned char lA[2][128 * 64];   // 16 KB
  __shared__ __align__(64) unsigned char lB[2][128 * 64];   // 16 KB
  const int tid  = threadIdx.x;
  const int wave = tid >> 6;          // 0..7
  const int lane = tid & 63;
  const int wm = wave >> 2;           // 0..1 : 64-row slice
  const int wn = wave & 3;            // 0..3 : 32-col slice
  const int m16  = lane & 15;
  const int quad = lane >> 4;

  // XCD-aware bijective swizzle over 1024 blocks (1024%8==0): each XCD gets
  // 128 consecutive tiles = 8 M-panels x all N x one K-half -> L2-local.
  const int fid = (blockIdx.z * 32 + blockIdx.y) * 16 + blockIdx.x;  // 0..1023
  const int swz = (fid & 7) * 128 + (fid >> 3);
  const int kh    = swz >> 9;              // K-half 0/1
  const int tileM = ((swz >> 4) & 31) * 128;
  const int tileN = (swz & 15) * 128;

  // fragment read offsets: 64B rows (K=64 fp8 per kstep).
  // MFMA h (k-half-of-step, K=32): lane reads bytes k = h*32 + quad*8 .. +7
  // chunk c = 2h + (quad>>1); swizzled slot = c ^ ((row>>1)&3)
  const int key  = (m16 >> 1) & 3;
  const int sub  = (quad & 1) * 8;
  const int rowA = (wm * 64 + m16) * 64;
  const int rowB = (wn * 32 + m16) * 64;
  int hOf[2];
#pragma unroll
  for (int h = 0; h < 2; ++h)
    hOf[h] = (((2 * h + (quad >> 1)) ^ key) << 4) + sub;

  // staging: 1 chunk/thread/matrix (8 KB per matrix per kstep, 512 threads);
  // global addr carries the XOR swizzle, LDS dest stays linear
  const int o = wave * 1024 + lane * 16;   // 0..8191
  const int r = o >> 6;                    // LDS row 0..127
  const int s = (o >> 4) & 3;              // LDS chunk slot
  const int q = s ^ ((r >> 1) & 3);        // logical (global) chunk
  const unsigned char* gA = W8  + (size_t)(tileM + r) * K_DIM + kh * K_HALF + q * 16;
  const unsigned char* gB = BT8 + (size_t)(tileN + r) * K_DIM + kh * K_HALF + q * 16;
  const int ldsOff = wave * 1024;          // wave-uniform base

  f32x4 acc[4][2];
#pragma unroll
  for (int i = 0; i < 4; ++i)
#pragma unroll
    for (int j = 0; j < 2; ++j) acc[i][j] = f32x4{0.f, 0.f, 0.f, 0.f};

  auto stage = [&](int buf, int kt_) {
    const size_t kb_ = (size_t)kt_ * 64;
    gl2lds16(gA + kb_, &lA[buf][ldsOff]);
    gl2lds16(gB + kb_, &lB[buf][ldsOff]);
  };
  auto compute = [&](int buf) {
#pragma unroll
    for (int h = 0; h < 2; ++h) {
      long long aF[4], bF[2];
#pragma unroll
      for (int i = 0; i < 4; ++i)
        aF[i] = *(const long long*)&lA[buf][rowA + i * 1024 + hOf[h]];
#pragma unroll
      for (int j = 0; j < 2; ++j)
        bF[j] = *(const long long*)&lB[buf][rowB + j * 1024 + hOf[h]];
#pragma unroll
      for (int i = 0; i < 4; ++i)
#pragma unroll
        for (int j = 0; j < 2; ++j)
          acc[i][j] = __builtin_amdgcn_mfma_f32_16x16x32_fp8_fp8(
              aF[i], bF[j], acc[i][j], 0, 0, 0);
    }
  };

  // prologue: tile 0 in flight (2 outstanding per wave)
  stage(0, 0);

#pragma unroll 1
  for (int kt = 0; kt < K_HALF / 64; kt += 2) {
    // even phase: prefetch kt+1, compute kt (buf0)
    stage(1, kt + 1);                                  // 4 outstanding
    asm volatile("s_waitcnt vmcnt(2)" ::: "memory");   // tile kt landed
    __builtin_amdgcn_s_barrier();
    asm volatile("" ::: "memory");
    compute(0);
    __builtin_amdgcn_s_barrier();
    asm volatile("" ::: "memory");

    // odd phase: prefetch kt+2, compute kt+1 (buf1)
    if (kt + 2 < K_HALF / 64) {
      stage(0, kt + 2);
      asm volatile("s_waitcnt vmcnt(2)" ::: "memory");
    } else {
      asm volatile("s_waitcnt vmcnt(0)" ::: "memory");
    }
    __builtin_amdgcn_s_barrier();
    asm volatile("" ::: "memory");
    compute(1);
    __builtin_amdgcn_s_barrier();
    asm volatile("" ::: "memory");
  }

  // Epilogue: out[gm][gn] += softplus(b0+b1*(gn+25)) * (S[gm][gn]*[kh==0] + C_half)
#pragma unroll
  for (int j = 0; j < 2; ++j) {
    int gn = tileN + wn * 32 + j * 16 + m16;
    if (gn >= N_OUT) continue;
    float tval = (float)(gn + WIN);
#pragma unroll
    for (int i = 0; i < 4; ++i) {
#pragma unroll
      for (int r2 = 0; r2 < 4; ++r2) {
        int gm = tileM + wm * 64 + i * 16 + quad * 4 + r2;
        float x = b0[gm] + b1[gm] * tval;
        float beta = fmaxf(x, 0.f) + log1pf(__expf(-fabsf(x)));
        float sv = (kh == 0) ? bf2f(Sbf[(size_t)gm * N_PAD + gn]) : 0.f;
        unsafeAtomicAdd(&out[(size_t)gm * N_OUT + gn],
                        beta * (sv + acc[i][j][r2]));
      }
    }
  }
}

extern "C" void kernel_launch(void* const* d_in, const int* in_sizes, int n_in,
                              void* d_out, int out_size, void* d_ws, size_t ws_size,
                              hipStream_t stream) {
  const float* ys     = (const float*)d_in[0];
  const float* alphas = (const float*)d_in[1];
  const float* repro  = (const float*)d_in[2];
  const float* b0     = (const float*)d_in[3];
  const float* b1     = (const float*)d_in[4];
  float* out = (float*)d_out;

  char* ws = (char*)d_ws;
  unsigned char*  W8  = (unsigned char*)ws;                                    // 16 MiB
  unsigned char*  BT8 = (unsigned char*)(ws + (size_t)M_DIM * K_DIM);          //  8 MiB
  unsigned short* Sbf = (unsigned short*)(ws + (size_t)M_DIM * K_DIM
                                             + (size_t)N_PAD * K_DIM);         // 16 MiB

  k_prep<<<NB_PREP, 256, 0, stream>>>(alphas, ys, repro, W8, BT8, Sbf, out);
  k_gemm<<<dim3(N_PAD / 128, M_DIM / 128, 2), 512, 0, stream>>>(W8, BT8, Sbf,
                                                                b0, b1, out);
}

// Round 4
// 258.619 us; speedup vs baseline: 1.4261x; 1.4261x over previous
//
#include <hip/hip_runtime.h>
#include <stdint.h>

#define M_DIM 4096
#define T_DIM 2048
#define N_OUT 2024
#define N_PAD 2048
#define WIN   25
#define K_DIM 4096

typedef float f32x4 __attribute__((ext_vector_type(4)));

__device__ __forceinline__ unsigned short f2bf(float x) {
  unsigned u = __float_as_uint(x);
  u += 0x7FFF + ((u >> 16) & 1);           // round-to-nearest-even
  return (unsigned short)(u >> 16);
}
__device__ __forceinline__ float bf2f(unsigned short h) {
  return __uint_as_float(((unsigned)h) << 16);
}

__device__ __forceinline__ void gl2lds16(const void* g, void* l) {
  // 16B-wide async global->LDS; HW dest = wave-uniform base + lane*16
  __builtin_amdgcn_global_load_lds(
      (const __attribute__((address_space(1))) unsigned int*)g,
      (__attribute__((address_space(3))) unsigned int*)l, 16, 0, 0);
}

// pack 4 floats -> 4 e4m3 bytes (one dword)
__device__ __forceinline__ int pk_fp8x4(float a, float b, float c, float d) {
  int w = __builtin_amdgcn_cvt_pk_fp8_f32(a, b, 0, false);
  w = __builtin_amdgcn_cvt_pk_fp8_f32(c, d, w, true);
  return w;
}

// ---------- Fused prep: wcast | conv | transpose ----------
// Block ranges:
//   [0, 8192)          : W8 = e4m3(sigmoid(alphas)), diag -> 0
//   [8192, 40960)      : Sbf = bf16(softplus(depthwise_conv(ys, repro)))
//   [40960, 43008)     : BT8[n][k] = e4m3(ys[k][n+24]), zero-pad n>=2024
// R11: out-zero range removed (no atomic combine anymore).
#define NB_WCAST 8192
#define NB_CONV  32768
#define NB_TRANS 2048
#define B_CONV   NB_WCAST
#define B_TRANS  (B_CONV + NB_CONV)
#define NB_PREP  (B_TRANS + NB_TRANS)

__global__ __launch_bounds__(256) void k_prep(const float* __restrict__ alphas,
                                              const float* __restrict__ ys,
                                              const float* __restrict__ repro,
                                              unsigned char* __restrict__ W8,
                                              unsigned char* __restrict__ BT8,
                                              unsigned short* __restrict__ Sbf) {
  __shared__ __align__(16) char smem[64 * 65 * 4];   // max of branch needs (16.6 KB)
  const int bid = blockIdx.x;
  const int tid = threadIdx.x;

  if (bid < B_CONV) {
    // ---- wcast ----
    size_t i8 = ((size_t)bid * 256 + tid) * 8;
    const float4 v0 = *(const float4*)(alphas + i8);
    const float4 v1 = *(const float4*)(alphas + i8 + 4);
    int row = (int)(i8 >> 12);
    int col = (int)(i8 & 4095);
    float a[8] = {v0.x, v0.y, v0.z, v0.w, v1.x, v1.y, v1.z, v1.w};
    float w[8];
#pragma unroll
    for (int j = 0; j < 8; ++j)
      w[j] = (row == col + j) ? 0.f : 1.f / (1.f + __expf(-a[j]));
    int p0 = pk_fp8x4(w[0], w[1], w[2], w[3]);
    int p1 = pk_fp8x4(w[4], w[5], w[6], w[7]);
    *(uint2*)(W8 + i8) = uint2{(unsigned)p0, (unsigned)p1};
  } else if (bid < B_TRANS) {
    // ---- conv ----
    float* sy = (float*)smem;          // 280 floats
    float* sr = sy + 280;              // 25 floats
    int b  = bid - B_CONV;
    int m  = b >> 3;
    int j0 = (b & 7) * 256;
    sy[tid] = ys[(size_t)m * T_DIM + j0 + tid];
    if (tid < WIN - 1) {
      int jj = j0 + 256 + tid;
      sy[256 + tid] = (jj < T_DIM) ? ys[(size_t)m * T_DIM + jj] : 0.f;
    }
    if (tid < WIN) sr[tid] = repro[m * WIN + tid];
    __syncthreads();
    int j = j0 + tid;
    float z = 0.f;
#pragma unroll
    for (int k = 0; k < WIN; ++k) z += sy[tid + k] * sr[k];
    float sp = fmaxf(z, 0.f) + log1pf(__expf(-fabsf(z)));
    Sbf[(size_t)m * N_PAD + j] = (j < N_OUT) ? f2bf(sp) : (unsigned short)0;
  } else {
    // ---- transpose ----
    float (*t)[65] = (float (*)[65])smem;
    int b  = bid - B_TRANS;
    int n0 = (b & 31) * 64;
    int k0 = (b >> 5) * 64;
    int tx = tid & 63;
    int ty = tid >> 6;
#pragma unroll
    for (int r = 0; r < 16; ++r) {
      int kk = k0 + ty + r * 4;
      int n = n0 + tx;
      t[ty + r * 4][tx] = (n < N_OUT) ? ys[(size_t)kk * T_DIM + n + (WIN - 1)] : 0.f;
    }
    __syncthreads();
    int nl = tid >> 2;
    int kc = (tid & 3) * 16;
    unsigned wds[4];
#pragma unroll
    for (int w = 0; w < 4; ++w)
      wds[w] = (unsigned)pk_fp8x4(t[kc + 4 * w][nl], t[kc + 4 * w + 1][nl],
                                  t[kc + 4 * w + 2][nl], t[kc + 4 * w + 3][nl]);
    *(uint4*)(BT8 + (size_t)(n0 + nl) * K_DIM + k0 + kc) =
        uint4{wds[0], wds[1], wds[2], wds[3]};
  }
}

// ---------- GEMM: C = W8 @ BT8^T (fp8 MFMA), out = beta * (S + C) ----------
// R11: 32 waves/CU WITHOUT split-K. R10 post-mortem: 16.6M memory-side
// atomic RMWs (WRITE_SIZE 37->397 MB) turned the epilogue into an HBM pass;
// split-K via atomics is dead for a 33 MB output. The R8->R9 law stands
// (throughput = resident waves / kstep latency), so reach the 32-wave cap
// by thread count instead: 512 blocks x 1024 threads (16 waves, wave=32x32,
// acc 16 VGPR). 2 blocks/CU x 16 waves = 32 waves/CU; launch_bounds(1024,8)
// keeps VGPR<=64 (the 32-wave condition). LDS 4buf x 16KB = 64KB/block ->
// 128KB/CU. Waves 0-7 stage A, 8-15 stage B (1 gl2lds/wave/tile, vmcnt(3)
// at prefetch distance 3). Single K-sweep, direct stores, accumulation
// order identical to R9 -> identical numerics.
__global__ __launch_bounds__(1024, 8) void k_gemm(const unsigned char* __restrict__ W8,
                                                  const unsigned char* __restrict__ BT8,
                                                  const unsigned short* __restrict__ Sbf,
                                                  const float* __restrict__ b0,
                                                  const float* __restrict__ b1,
                                                  float* __restrict__ out) {
  __shared__ __align__(64) unsigned char lA[4][128 * 64];   // 32 KB
  __shared__ __align__(64) unsigned char lB[4][128 * 64];   // 32 KB
  const int tid  = threadIdx.x;
  const int wave = tid >> 6;          // 0..15
  const int lane = tid & 63;
  const int wm = wave >> 2;           // 0..3 : 32-row slice
  const int wn = wave & 3;            // 0..3 : 32-col slice
  const int m16  = lane & 15;
  const int quad = lane >> 4;

  // XCD-aware bijective swizzle (512%8==0): each XCD gets 64 consecutive
  // tiles = 4 full M-rows -> A-panels L2-local.
  const int fid  = blockIdx.y * gridDim.x + blockIdx.x;   // 0..511
  const int swz  = (fid & 7) * 64 + (fid >> 3);
  const int tileN = (swz & 15) * 128;
  const int tileM = (swz >> 4) * 128;

  // fragment read offsets: 64B rows (K=64 fp8 per kstep).
  // MFMA h (k-half, K=32): lane reads bytes k = h*32 + quad*8 .. +7
  // chunk c = 2h + (quad>>1); swizzled slot = c ^ ((row>>1)&3); row%16==m16
  // and row/16 even multiples -> key = (m16>>1)&3 unchanged.
  const int key  = (m16 >> 1) & 3;
  const int sub  = (quad & 1) * 8;
  const int rowA = (wm * 32 + m16) * 64;
  const int rowB = (wn * 32 + m16) * 64;
  int hOf[2];
#pragma unroll
  for (int h = 0; h < 2; ++h)
    hOf[h] = (((2 * h + (quad >> 1)) ^ key) << 4) + sub;

  // staging: waves 0-7 stage A (8KB), waves 8-15 stage B (8KB); 16B/thread.
  // Global addr carries the XOR chunk swizzle, LDS dest stays linear.
  const int sw = wave & 7;
  const int o  = sw * 1024 + lane * 16;    // 0..8191
  const int r  = o >> 6;                   // LDS row 0..127
  const int s  = (o >> 4) & 3;             // LDS chunk slot
  const int q  = s ^ ((r >> 1) & 3);       // logical (global) chunk
  const bool isA = (wave < 8);
  const unsigned char* gSrc =
      (isA ? W8 + (size_t)(tileM + r) * K_DIM
           : BT8 + (size_t)(tileN + r) * K_DIM) + q * 16;
  const int ldsOff = sw * 1024;            // wave-uniform base

  f32x4 acc[2][2];
#pragma unroll
  for (int i = 0; i < 2; ++i)
#pragma unroll
    for (int j = 0; j < 2; ++j) acc[i][j] = f32x4{0.f, 0.f, 0.f, 0.f};

  // tile t lives in buffer t & 3; 1 gl2lds (vmcnt event) per tile per wave
  auto stage = [&](int buf, int kt_) {
    const size_t kb_ = (size_t)kt_ * 64;
    gl2lds16(gSrc + kb_, (isA ? &lA[buf][ldsOff] : &lB[buf][ldsOff]));
  };
  auto compute = [&](int buf) {
#pragma unroll
    for (int h = 0; h < 2; ++h) {
      long long aF[2], bF[2];
#pragma unroll
      for (int i = 0; i < 2; ++i)
        aF[i] = *(const long long*)&lA[buf][rowA + i * 1024 + hOf[h]];
#pragma unroll
      for (int j = 0; j < 2; ++j)
        bF[j] = *(const long long*)&lB[buf][rowB + j * 1024 + hOf[h]];
#pragma unroll
      for (int i = 0; i < 2; ++i)
#pragma unroll
        for (int j = 0; j < 2; ++j)
          acc[i][j] = __builtin_amdgcn_mfma_f32_16x16x32_fp8_fp8(
              aF[i], bF[j], acc[i][j], 0, 0, 0);
    }
  };

  // prologue: tiles 0,1,2 in flight (3 outstanding per wave)
  stage(0, 0);
  stage(1, 1);
  stage(2, 2);

#pragma unroll 1
  for (int kt = 0; kt < K_DIM / 64; kt += 4) {
    // phase 0: prefetch kt+3 (kt<=60 -> always valid), compute kt (buf0)
    stage(3, kt + 3);                                  // 4 outstanding
    asm volatile("s_waitcnt vmcnt(3)" ::: "memory");   // tile kt landed
    __builtin_amdgcn_s_barrier();
    asm volatile("" ::: "memory");
    compute(0);
    __builtin_amdgcn_s_barrier();                      // buf0 free for reuse
    asm volatile("" ::: "memory");

    // phase 1: prefetch kt+4, compute kt+1 (buf1)
    if (kt + 4 < K_DIM / 64) {
      stage(0, kt + 4);
      asm volatile("s_waitcnt vmcnt(3)" ::: "memory");
    } else {
      asm volatile("s_waitcnt vmcnt(2)" ::: "memory");
    }
    __builtin_amdgcn_s_barrier();
    asm volatile("" ::: "memory");
    compute(1);
    __builtin_amdgcn_s_barrier();
    asm volatile("" ::: "memory");

    // phase 2: prefetch kt+5, compute kt+2 (buf2)
    if (kt + 5 < K_DIM / 64) {
      stage(1, kt + 5);
      asm volatile("s_waitcnt vmcnt(3)" ::: "memory");
    } else {
      asm volatile("s_waitcnt vmcnt(1)" ::: "memory");
    }
    __builtin_amdgcn_s_barrier();
    asm volatile("" ::: "memory");
    compute(2);
    __builtin_amdgcn_s_barrier();
    asm volatile("" ::: "memory");

    // phase 3: prefetch kt+6, compute kt+3 (buf3)
    if (kt + 6 < K_DIM / 64) {
      stage(2, kt + 6);
      asm volatile("s_waitcnt vmcnt(3)" ::: "memory");
    } else {
      asm volatile("s_waitcnt vmcnt(0)" ::: "memory");
    }
    __builtin_amdgcn_s_barrier();
    asm volatile("" ::: "memory");
    compute(3);
    __builtin_amdgcn_s_barrier();
    asm volatile("" ::: "memory");
  }

  // Epilogue: out[gm][gn] = softplus(b0+b1*(gn+25)) * (S[gm][gn] + C)
#pragma unroll
  for (int j = 0; j < 2; ++j) {
    int gn = tileN + wn * 32 + j * 16 + m16;
    if (gn >= N_OUT) continue;
    float tval = (float)(gn + WIN);
#pragma unroll
    for (int i = 0; i < 2; ++i) {
#pragma unroll
      for (int r2 = 0; r2 < 4; ++r2) {
        int gm = tileM + wm * 32 + i * 16 + quad * 4 + r2;
        float x = b0[gm] + b1[gm] * tval;
        float beta = fmaxf(x, 0.f) + log1pf(__expf(-fabsf(x)));
        float sv = bf2f(Sbf[(size_t)gm * N_PAD + gn]);
        out[(size_t)gm * N_OUT + gn] = beta * (sv + acc[i][j][r2]);
      }
    }
  }
}

extern "C" void kernel_launch(void* const* d_in, const int* in_sizes, int n_in,
                              void* d_out, int out_size, void* d_ws, size_t ws_size,
                              hipStream_t stream) {
  const float* ys     = (const float*)d_in[0];
  const float* alphas = (const float*)d_in[1];
  const float* repro  = (const float*)d_in[2];
  const float* b0     = (const float*)d_in[3];
  const float* b1     = (const float*)d_in[4];
  float* out = (float*)d_out;

  char* ws = (char*)d_ws;
  unsigned char*  W8  = (unsigned char*)ws;                                    // 16 MiB
  unsigned char*  BT8 = (unsigned char*)(ws + (size_t)M_DIM * K_DIM);          //  8 MiB
  unsigned short* Sbf = (unsigned short*)(ws + (size_t)M_DIM * K_DIM
                                             + (size_t)N_PAD * K_DIM);         // 16 MiB

  k_prep<<<NB_PREP, 256, 0, stream>>>(alphas, ys, repro, W8, BT8, Sbf);
  k_gemm<<<dim3(N_PAD / 128, M_DIM / 128), 1024, 0, stream>>>(W8, BT8, Sbf,
                                                              b0, b1, out);
}